// Round 1
// 487.939 us; speedup vs baseline: 1.0340x; 1.0340x over previous
//
#include <hip/hip_runtime.h>
#include <cstdint>

#define FP8_MAX 448.0f
#define EPSF 1.1920928955078125e-07f

typedef float floatx4 __attribute__((ext_vector_type(4)));

// sizes
#define BATCH 8
#define MDIM 2048
#define KDIM 2048
#define NDIM 2048
#define NELEM ((long)BATCH * MDIM * KDIM)   // 33554432 per tensor
#define N4 (NELEM / 4)

// ws layout: [0..7]: amax_x, amax_w (uint bits). [256 ..): qx bytes, then qwT bytes.
#define QX_OFF 256
#define QW_OFF (256 + NELEM)

static __device__ __forceinline__ float wave_max(float v) {
    #pragma unroll
    for (int off = 32; off > 0; off >>= 1)
        v = fmaxf(v, __shfl_xor(v, off, 64));
    return v;
}

__global__ void amax_kernel(const float4* __restrict__ x, const float4* __restrict__ w,
                            unsigned int* __restrict__ amax) {
    const float4* p = blockIdx.y ? w : x;
    unsigned int* outp = amax + blockIdx.y;
    long idx = (long)blockIdx.x * blockDim.x + threadIdx.x;
    long stride = (long)gridDim.x * blockDim.x;
    float m = 0.f;
    for (long i = idx; i < N4; i += stride) {
        float4 v = p[i];
        m = fmaxf(m, fmaxf(fmaxf(fabsf(v.x), fabsf(v.y)), fmaxf(fabsf(v.z), fabsf(v.w))));
    }
    m = wave_max(m);
    __shared__ float smax[4];
    int lane = threadIdx.x & 63, wv = threadIdx.x >> 6;
    if (lane == 0) smax[wv] = m;
    __syncthreads();
    if (threadIdx.x == 0) {
        m = fmaxf(fmaxf(smax[0], smax[1]), fmaxf(smax[2], smax[3]));
        atomicMax(outp, __float_as_uint(m));  // all values >= 0: uint order == float order
    }
}

static __device__ __forceinline__ uint32_t quant4(float4 v, float s) {
    float a = fminf(fmaxf(v.x * s, -FP8_MAX), FP8_MAX);
    float b = fminf(fmaxf(v.y * s, -FP8_MAX), FP8_MAX);
    float c = fminf(fmaxf(v.z * s, -FP8_MAX), FP8_MAX);
    float d = fminf(fmaxf(v.w * s, -FP8_MAX), FP8_MAX);
    uint32_t r = (uint32_t)__builtin_amdgcn_cvt_pk_fp8_f32(a, b, 0, false);
    r = (uint32_t)__builtin_amdgcn_cvt_pk_fp8_f32(c, d, (int)r, true);
    return r;  // bytes [x,y,z,w] little-endian
}

__global__ void quant_x_kernel(const float4* __restrict__ x, uint32_t* __restrict__ qx,
                               const unsigned int* __restrict__ amax) {
    float ax = fmaxf(__uint_as_float(amax[0]), EPSF);
    float s = FP8_MAX / ax;
    long idx = (long)blockIdx.x * blockDim.x + threadIdx.x;
    long stride = (long)gridDim.x * blockDim.x;
    for (long i = idx; i < N4; i += stride)
        qx[i] = quant4(x[i], s);
}

// quantize + transpose W: global [b][k][n] (n contiguous) -> qwT [b][n][k] (k contiguous)
// tile 64(k) x 64(n), LDS byte-transpose with padded stride 68.
__global__ void quant_w_kernel(const float* __restrict__ w, uint8_t* __restrict__ qwT,
                               const unsigned int* __restrict__ amax) {
    float aw = fmaxf(__uint_as_float(amax[1]), EPSF);
    float s = FP8_MAX / aw;
    __shared__ uint8_t ldsT[64 * 68];
    int t = threadIdx.x;
    int n0 = blockIdx.x * 64, k0 = blockIdx.y * 64;
    long base = (long)blockIdx.z * KDIM * NDIM;
    int nl = (t & 15) * 4;
    int kl = t >> 4;  // 0..15
    #pragma unroll
    for (int it = 0; it < 4; ++it) {
        int k = kl + it * 16;
        float4 v = *(const float4*)(w + base + (long)(k0 + k) * NDIM + n0 + nl);
        uint32_t r = quant4(v, s);
        ldsT[(nl + 0) * 68 + k] = (uint8_t)(r);
        ldsT[(nl + 1) * 68 + k] = (uint8_t)(r >> 8);
        ldsT[(nl + 2) * 68 + k] = (uint8_t)(r >> 16);
        ldsT[(nl + 3) * 68 + k] = (uint8_t)(r >> 24);
    }
    __syncthreads();
    int n = t >> 2, c = t & 3;
    const uint8_t* src = &ldsT[n * 68 + c * 16];
    uint4 d;
    d.x = *(const uint32_t*)(src + 0);
    d.y = *(const uint32_t*)(src + 4);
    d.z = *(const uint32_t*)(src + 8);
    d.w = *(const uint32_t*)(src + 12);
    *(uint4*)(qwT + base + (long)(n0 + n) * KDIM + k0 + c * 16) = d;
}

// ---------------------------------------------------------------------------
// GEMM: C[b][m][n] = (qx[b] . qwT[b]^T) * ds + bias[b][n]
// 256x256 tile, BK=64 bytes, 512 threads = 8 waves (2M x 4N), per-wave 8x4
// 16x16x32 fp8 MFMA fragments (128x64 output per wave).
//
// 4-phase-per-K-tile schedule with counted vmcnt (T3+T4) + setprio (T5):
//   LDS per buffer = A[kk][256][32B] (16KB) + B[kk][256][32B] (16KB); dbuf = 64KB.
//   Each 8KB K-half (A_k0/A_k1/B_k0/B_k1) = 1x global_load_lds(16B)/thread.
//   phase 1: read A(k0)x8 + B(k0,ni01)x2 ; stage A_k1(s+1) ; 16 MFMA
//   phase 2: read B(k0,ni23)x2          ; stage B_k1(s+1) ; 16 MFMA ; vmcnt(4)
//   phase 3: read A(k1)x8 + B(k1,ni23)x2; stage A_k0(s+2) ; 16 MFMA
//   phase 4: read B(k1,ni01)x2          ; stage B_k0(s+2) ; 16 MFMA ; vmcnt(4)
// Each restage target's last ds_read is >=1 barrier-pair earlier (A_k0 last read
// p2 -> restaged p3 two tiles later in same buffer; B_k0 p2->p4; A_k1/B_k1
// p3/p4 -> next tile p1/p2). Steady state keeps 4 loads in flight across
// barriers (never drains vmcnt to 0 in the main loop); tail tiles use 2/0.
//
// Swizzle: within each 32B K-half row, 16B slot = chunk ^ ((row>>2)&1), applied
// on the GLOBAL source address at staging (LDS dest stays lane-linear for
// global_load_lds) and on the LDS address at fragment-read time -> 8 distinct
// start banks per 16-lane group (2-way aliasing = free).
// ---------------------------------------------------------------------------
#define BM 256
#define BN 256
#define BK 64
#define NT (KDIM / BK)   // 32

__global__ __launch_bounds__(512, 2) void gemm_kernel(const uint8_t* __restrict__ qx,
                                                      const uint8_t* __restrict__ qwT,
                                                      const float* __restrict__ bias,
                                                      float* __restrict__ out,
                                                      const unsigned int* __restrict__ amax) {
    int b = blockIdx.z;
    int tm = blockIdx.y, tn = blockIdx.x;
    __shared__ uint8_t lds[65536];
    int t = threadIdx.x, lane = t & 63, wv = t >> 6;
    int wm = wv & 1, wn = wv >> 1;           // 2 x 4 wave grid
    int m = lane & 15, g = lane >> 4;
    int gh = g >> 1, glo8 = (g & 1) * 8;

    const uint8_t* Ab = qx + (long)b * MDIM * KDIM + (long)tm * BM * KDIM;
    const uint8_t* Bb = qwT + (long)b * NDIM * KDIM + (long)tn * BN * KDIM;

    // staging: thread t stages 16B of a K-half: row = t>>1 (0..255), slot = t&1,
    // source logical chunk = slot ^ ((row>>2)&1)  (inverse == forward swizzle)
    int srow = t >> 1;
    int sc16 = ((t & 1) ^ ((srow >> 2) & 1)) * 16;
    const uint8_t* asrc = Ab + (long)srow * KDIM + sc16;
    const uint8_t* bsrc = Bb + (long)srow * KDIM + sc16;

#define STAGE(s_, isB_, h_) do {                                                              \
    const uint8_t* _src = ((isB_) ? bsrc : asrc) + (long)(s_) * BK + (h_) * 32;               \
    __builtin_amdgcn_global_load_lds(                                                         \
        (const __attribute__((address_space(1))) uint32_t*)_src,                              \
        (__attribute__((address_space(3))) uint32_t*)(lds + (((s_) & 1) << 15) +              \
            (isB_) * 16384 + (h_) * 8192 + t * 16), 16, 0, 0);                                \
} while (0)

    // fragment read byte-offsets within an 8KB K-half (kk adds +8192, B adds +16384)
    int aoff[8];
    #pragma unroll
    for (int mi = 0; mi < 8; ++mi) {
        int r = wm * 128 + mi * 16 + m;
        aoff[mi] = r * 32 + ((gh ^ ((r >> 2) & 1)) * 16) + glo8;
    }
    int boff[4];
    #pragma unroll
    for (int ni = 0; ni < 4; ++ni) {
        int r = wn * 64 + ni * 16 + m;
        boff[ni] = 16384 + r * 32 + ((gh ^ ((r >> 2) & 1)) * 16) + glo8;
    }

    floatx4 acc[8][4] = {};
    long a0[8], bq[2];

    // prologue: tile0 all 4 halves + tile1 k0 halves (oldest-first for vmcnt math)
    STAGE(0, 0, 0); STAGE(0, 1, 0); STAGE(0, 0, 1); STAGE(0, 1, 1);
    STAGE(1, 0, 0); STAGE(1, 1, 0);
    asm volatile("s_waitcnt vmcnt(4)" ::: "memory");   // tile0 k0 halves landed
    __builtin_amdgcn_s_barrier();

    #pragma unroll 2
    for (int s = 0; s < NT; ++s) {
        const uint8_t* L = lds + ((s & 1) << 15);

        // ---- phase 1: kk=0, ni 0..1 ----
        #pragma unroll
        for (int mi = 0; mi < 8; ++mi) a0[mi] = *(const long*)(L + aoff[mi]);
        bq[0] = *(const long*)(L + boff[0]);
        bq[1] = *(const long*)(L + boff[1]);
        if (s + 1 < NT) STAGE(s + 1, 0, 1);            // A_k1(s+1)
        __builtin_amdgcn_s_barrier();
        asm volatile("s_waitcnt lgkmcnt(0)" ::: "memory");
        __builtin_amdgcn_sched_barrier(0);
        __builtin_amdgcn_s_setprio(1);
        #pragma unroll
        for (int mi = 0; mi < 8; ++mi) {
            acc[mi][0] = __builtin_amdgcn_mfma_f32_16x16x32_fp8_fp8(a0[mi], bq[0], acc[mi][0], 0, 0, 0);
            acc[mi][1] = __builtin_amdgcn_mfma_f32_16x16x32_fp8_fp8(a0[mi], bq[1], acc[mi][1], 0, 0, 0);
        }
        __builtin_amdgcn_s_setprio(0);
        __builtin_amdgcn_s_barrier();

        // ---- phase 2: kk=0, ni 2..3 (reuse a0) ----
        bq[0] = *(const long*)(L + boff[2]);
        bq[1] = *(const long*)(L + boff[3]);
        if (s + 1 < NT) STAGE(s + 1, 1, 1);            // B_k1(s+1)
        __builtin_amdgcn_s_barrier();
        asm volatile("s_waitcnt lgkmcnt(0)" ::: "memory");
        __builtin_amdgcn_sched_barrier(0);
        __builtin_amdgcn_s_setprio(1);
        #pragma unroll
        for (int mi = 0; mi < 8; ++mi) {
            acc[mi][2] = __builtin_amdgcn_mfma_f32_16x16x32_fp8_fp8(a0[mi], bq[0], acc[mi][2], 0, 0, 0);
            acc[mi][3] = __builtin_amdgcn_mfma_f32_16x16x32_fp8_fp8(a0[mi], bq[1], acc[mi][3], 0, 0, 0);
        }
        __builtin_amdgcn_s_setprio(0);
        if (s < NT - 1) asm volatile("s_waitcnt vmcnt(4)" ::: "memory");  // k1(s) halves landed
        else            asm volatile("s_waitcnt vmcnt(0)" ::: "memory");
        __builtin_amdgcn_s_barrier();

        // ---- phase 3: kk=1, ni 2..3 ----
        #pragma unroll
        for (int mi = 0; mi < 8; ++mi) a0[mi] = *(const long*)(L + 8192 + aoff[mi]);
        bq[0] = *(const long*)(L + 8192 + boff[2]);
        bq[1] = *(const long*)(L + 8192 + boff[3]);
        if (s + 2 < NT) STAGE(s + 2, 0, 0);            // A_k0(s+2), current buf: last read p1
        __builtin_amdgcn_s_barrier();
        asm volatile("s_waitcnt lgkmcnt(0)" ::: "memory");
        __builtin_amdgcn_sched_barrier(0);
        __builtin_amdgcn_s_setprio(1);
        #pragma unroll
        for (int mi = 0; mi < 8; ++mi) {
            acc[mi][2] = __builtin_amdgcn_mfma_f32_16x16x32_fp8_fp8(a0[mi], bq[0], acc[mi][2], 0, 0, 0);
            acc[mi][3] = __builtin_amdgcn_mfma_f32_16x16x32_fp8_fp8(a0[mi], bq[1], acc[mi][3], 0, 0, 0);
        }
        __builtin_amdgcn_s_setprio(0);
        __builtin_amdgcn_s_barrier();

        // ---- phase 4: kk=1, ni 0..1 (reuse a0) ----
        bq[0] = *(const long*)(L + 8192 + boff[0]);
        bq[1] = *(const long*)(L + 8192 + boff[1]);
        if (s + 2 < NT) STAGE(s + 2, 1, 0);            // B_k0(s+2), current buf: last read p2
        __builtin_amdgcn_s_barrier();
        asm volatile("s_waitcnt lgkmcnt(0)" ::: "memory");
        __builtin_amdgcn_sched_barrier(0);
        __builtin_amdgcn_s_setprio(1);
        #pragma unroll
        for (int mi = 0; mi < 8; ++mi) {
            acc[mi][0] = __builtin_amdgcn_mfma_f32_16x16x32_fp8_fp8(a0[mi], bq[0], acc[mi][0], 0, 0, 0);
            acc[mi][1] = __builtin_amdgcn_mfma_f32_16x16x32_fp8_fp8(a0[mi], bq[1], acc[mi][1], 0, 0, 0);
        }
        __builtin_amdgcn_s_setprio(0);
        if (s < NT - 2)       asm volatile("s_waitcnt vmcnt(4)" ::: "memory");  // k0(s+1) landed
        else if (s == NT - 2) asm volatile("s_waitcnt vmcnt(2)" ::: "memory");
        __builtin_amdgcn_s_barrier();
    }
#undef STAGE

    float ax = fmaxf(__uint_as_float(amax[0]), EPSF);
    float aw = fmaxf(__uint_as_float(amax[1]), EPSF);
    float dsc = (ax / FP8_MAX) * (aw / FP8_MAX);  // 1/(sx*sw)

    #pragma unroll
    for (int ni = 0; ni < 4; ++ni) {
        int col = tn * BN + wn * 64 + ni * 16 + m;
        float bv = bias[(long)b * NDIM + col];
        #pragma unroll
        for (int mi = 0; mi < 8; ++mi) {
            int row0 = tm * BM + wm * 128 + mi * 16 + g * 4;
            #pragma unroll
            for (int r = 0; r < 4; ++r)
                out[((long)b * MDIM + row0 + r) * NDIM + col] = acc[mi][ni][r] * dsc + bv;
        }
    }
}

extern "C" void kernel_launch(void* const* d_in, const int* in_sizes, int n_in,
                              void* d_out, int out_size, void* d_ws, size_t ws_size,
                              hipStream_t stream) {
    const float* x = (const float*)d_in[0];
    const float* w = (const float*)d_in[1];
    const float* bias = (const float*)d_in[2];
    float* out = (float*)d_out;

    unsigned int* amax = (unsigned int*)d_ws;
    uint8_t* qx = (uint8_t*)d_ws + QX_OFF;
    uint8_t* qwT = (uint8_t*)d_ws + QW_OFF;
    (void)in_sizes; (void)n_in; (void)out_size; (void)ws_size;

    // zero the amax accumulators (ws is poisoned 0xAA before every launch)
    hipMemsetAsync(d_ws, 0, 8, stream);

    amax_kernel<<<dim3(2048, 2), 256, 0, stream>>>((const float4*)x, (const float4*)w, amax);
    quant_x_kernel<<<8192, 256, 0, stream>>>((const float4*)x, (uint32_t*)qx, amax);
    quant_w_kernel<<<dim3(NDIM / 64, KDIM / 64, BATCH), 256, 0, stream>>>(w, qwT, amax);
    gemm_kernel<<<dim3(NDIM / BN, MDIM / BM, BATCH), 512, 0, stream>>>(qx, qwT, bias, out, amax);
}

// Round 2
// 454.918 us; speedup vs baseline: 1.1091x; 1.0726x over previous
//
#include <hip/hip_runtime.h>
#include <cstdint>

#define FP8_MAX 448.0f
#define EPSF 1.1920928955078125e-07f

typedef float floatx4 __attribute__((ext_vector_type(4)));
typedef float floatx16 __attribute__((ext_vector_type(16)));
typedef int intx4 __attribute__((ext_vector_type(4)));
typedef int intx8 __attribute__((ext_vector_type(8)));

// sizes
#define BATCH 8
#define MDIM 2048
#define KDIM 2048
#define NDIM 2048
#define NELEM ((long)BATCH * MDIM * KDIM)   // 33554432 per tensor
#define N4 (NELEM / 4)

// ws layout: [0..7]: amax_x, amax_w (uint bits). [256 ..): qx bytes, then qwT bytes.
#define QX_OFF 256
#define QW_OFF (256 + NELEM)

static __device__ __forceinline__ float wave_max(float v) {
    #pragma unroll
    for (int off = 32; off > 0; off >>= 1)
        v = fmaxf(v, __shfl_xor(v, off, 64));
    return v;
}

// grid fixed at (2048,2)x256: N4 / (2048*256) == 16 trips exactly.
#define AMAX_BLOCKS 2048
__global__ void amax_kernel(const float4* __restrict__ x, const float4* __restrict__ w,
                            unsigned int* __restrict__ amax) {
    const float4* p = blockIdx.y ? w : x;
    unsigned int* outp = amax + blockIdx.y;
    long idx = (long)blockIdx.x * blockDim.x + threadIdx.x;
    const long stride = (long)AMAX_BLOCKS * 256;
    float m0 = 0.f, m1 = 0.f;
    #pragma unroll
    for (int it = 0; it < 16; it += 2) {
        float4 v0 = p[idx + (long)it * stride];
        float4 v1 = p[idx + (long)(it + 1) * stride];
        m0 = fmaxf(m0, fmaxf(fmaxf(fabsf(v0.x), fabsf(v0.y)), fmaxf(fabsf(v0.z), fabsf(v0.w))));
        m1 = fmaxf(m1, fmaxf(fmaxf(fabsf(v1.x), fabsf(v1.y)), fmaxf(fabsf(v1.z), fabsf(v1.w))));
    }
    float m = wave_max(fmaxf(m0, m1));
    __shared__ float smax[4];
    int lane = threadIdx.x & 63, wv = threadIdx.x >> 6;
    if (lane == 0) smax[wv] = m;
    __syncthreads();
    if (threadIdx.x == 0) {
        m = fmaxf(fmaxf(smax[0], smax[1]), fmaxf(smax[2], smax[3]));
        atomicMax(outp, __float_as_uint(m));  // all values >= 0: uint order == float order
    }
}

static __device__ __forceinline__ uint32_t quant4(float4 v, float s) {
    float a = fminf(fmaxf(v.x * s, -FP8_MAX), FP8_MAX);
    float b = fminf(fmaxf(v.y * s, -FP8_MAX), FP8_MAX);
    float c = fminf(fmaxf(v.z * s, -FP8_MAX), FP8_MAX);
    float d = fminf(fmaxf(v.w * s, -FP8_MAX), FP8_MAX);
    uint32_t r = (uint32_t)__builtin_amdgcn_cvt_pk_fp8_f32(a, b, 0, false);
    r = (uint32_t)__builtin_amdgcn_cvt_pk_fp8_f32(c, d, (int)r, true);
    return r;  // bytes [x,y,z,w] little-endian
}

// grid fixed at 8192x256: N4 / (8192*256) == 4 trips exactly; unrolled for 4 outstanding loads.
#define QX_BLOCKS 8192
__global__ void quant_x_kernel(const float4* __restrict__ x, uint32_t* __restrict__ qx,
                               const unsigned int* __restrict__ amax) {
    float ax = fmaxf(__uint_as_float(amax[0]), EPSF);
    float s = FP8_MAX / ax;
    long idx = (long)blockIdx.x * blockDim.x + threadIdx.x;
    const long stride = (long)QX_BLOCKS * 256;
    #pragma unroll
    for (int it = 0; it < 4; ++it) {
        long i = idx + (long)it * stride;
        qx[i] = quant4(x[i], s);
    }
}

// quantize + transpose W: global [b][k][n] (n contiguous) -> qwT [b][n][k] (k contiguous)
// tile 64(k) x 64(n), LDS byte-transpose with padded stride 68.
__global__ void quant_w_kernel(const float* __restrict__ w, uint8_t* __restrict__ qwT,
                               const unsigned int* __restrict__ amax) {
    float aw = fmaxf(__uint_as_float(amax[1]), EPSF);
    float s = FP8_MAX / aw;
    __shared__ uint8_t ldsT[64 * 68];
    int t = threadIdx.x;
    int n0 = blockIdx.x * 64, k0 = blockIdx.y * 64;
    long base = (long)blockIdx.z * KDIM * NDIM;
    int nl = (t & 15) * 4;
    int kl = t >> 4;  // 0..15
    #pragma unroll
    for (int it = 0; it < 4; ++it) {
        int k = kl + it * 16;
        float4 v = *(const float4*)(w + base + (long)(k0 + k) * NDIM + n0 + nl);
        uint32_t r = quant4(v, s);
        ldsT[(nl + 0) * 68 + k] = (uint8_t)(r);
        ldsT[(nl + 1) * 68 + k] = (uint8_t)(r >> 8);
        ldsT[(nl + 2) * 68 + k] = (uint8_t)(r >> 16);
        ldsT[(nl + 3) * 68 + k] = (uint8_t)(r >> 24);
    }
    __syncthreads();
    int n = t >> 2, c = t & 3;
    const uint8_t* src = &ldsT[n * 68 + c * 16];
    uint4 d;
    d.x = *(const uint32_t*)(src + 0);
    d.y = *(const uint32_t*)(src + 4);
    d.z = *(const uint32_t*)(src + 8);
    d.w = *(const uint32_t*)(src + 12);
    *(uint4*)(qwT + base + (long)(n0 + n) * KDIM + k0 + c * 16) = d;
}

// ---------------------------------------------------------------------------
// GEMM: C[b][m][n] = (qx[b] . qwT[b]^T) * ds + bias[b][n]
// 256x256 tile, BK=64, 512 threads = 8 waves (2M x 4N), wave tile 128x64 via
// 4x2 mfma_scale_f32_32x32x64_f8f6f4 (unit E8M0 scales = 0x7f -> exact fp8
// product at 2x the non-scaled fp8 rate). One MFMA consumes a lane's full
// 32 contiguous K-bytes: lane l -> row l&31, K-half l>>5 (the MX-block layout).
//
// LDS: triple buffer x (A 16KB + B 16KB) = 96KB. One tile = 4 stage units of
// 8KB (512 thr x 16B). Layout [256 rows][64B], 16B-chunk swizzle
// c_phys = c ^ ((row>>1)&3): 8 consecutive rows hit 8 distinct start banks ->
// 4-way residual on ds_read_b128 (structural floor at 16B stage granularity).
// Swizzle applied on the GLOBAL source address (LDS dest stays lane-linear for
// global_load_lds) and on the LDS address at read time.
//
// Schedule (T3+T4+T5): 1 barrier-pair per K-tile; stage tile s+2 during tile s
// (its buffer's reads finished at tile s-1's closing barrier); counted
// vmcnt(4) at tile end keeps tile-(s+2) loads in flight while ensuring
// tile-(s+1) landed -> ~2 phases (>2000 cyc) of HBM slack, never drains in
// the main loop. setprio(1) wraps the 8-MFMA cluster.
// ---------------------------------------------------------------------------
#define BM 256
#define BN 256
#define BK 64
#define NT (KDIM / BK)   // 32

__global__ __launch_bounds__(512, 2) void gemm_kernel(const uint8_t* __restrict__ qx,
                                                      const uint8_t* __restrict__ qwT,
                                                      const float* __restrict__ bias,
                                                      float* __restrict__ out,
                                                      const unsigned int* __restrict__ amax) {
    int b = blockIdx.z;
    int tm = blockIdx.y, tn = blockIdx.x;
    __shared__ uint8_t lds[98304];  // 3 x (16KB A + 16KB B)
    int t = threadIdx.x, lane = t & 63, wv = t >> 6;
    int wm = wv >> 2, wn = wv & 3;     // 2 x 4 wave grid
    int rl = lane & 31, kh = lane >> 5;

    const uint8_t* Ab = qx + (long)b * MDIM * KDIM + (long)tm * BM * KDIM;
    const uint8_t* Bb = qwT + (long)b * NDIM * KDIM + (long)tn * BN * KDIM;

    // staging: thread t covers row (t>>2) [+128 for unit 1], phys chunk t&3;
    // logical source chunk = (t&3) ^ ((row>>1)&3); (row>>1)&3 == (t>>3)&3 for both units.
    long stoff = (long)(t >> 2) * KDIM + (long)(((t & 3) ^ ((t >> 3) & 3)) << 4);

#define STAGE(base_, isB_, u_, kt_) do {                                                      \
    const uint8_t* _s = ((isB_) ? Bb : Ab) + stoff + (long)(u_) * (128L * KDIM)               \
                        + (long)(kt_) * BK;                                                   \
    __builtin_amdgcn_global_load_lds(                                                         \
        (const __attribute__((address_space(1))) uint32_t*)_s,                                \
        (__attribute__((address_space(3))) uint32_t*)(lds + (base_) + (isB_) * 16384 +        \
            (u_) * 8192 + t * 16), 16, 0, 0);                                                 \
} while (0)

    // fragment read byte-offsets (first 16B chunk; second is addr^16 since
    // swizzled chunk index flips bit0 for c -> c+1)
    int aoff[4];
    #pragma unroll
    for (int mi = 0; mi < 4; ++mi) {
        int r = wm * 128 + mi * 32 + rl;
        aoff[mi] = r * 64 + ((((kh * 2) ^ ((r >> 1) & 3))) << 4);
    }
    int boff[2];
    #pragma unroll
    for (int ni = 0; ni < 2; ++ni) {
        int r = wn * 64 + ni * 32 + rl;
        boff[ni] = 16384 + r * 64 + ((((kh * 2) ^ ((r >> 1) & 3))) << 4);
    }

    floatx16 acc[4][2] = {};

    // prologue: stage tiles 0 and 1 (oldest-first), wait tile0's 4 units
    STAGE(0, 0, 0, 0); STAGE(0, 0, 1, 0); STAGE(0, 1, 0, 0); STAGE(0, 1, 1, 0);
    STAGE(32768, 0, 0, 1); STAGE(32768, 0, 1, 1); STAGE(32768, 1, 0, 1); STAGE(32768, 1, 1, 1);
    asm volatile("s_waitcnt vmcnt(4)" ::: "memory");
    __builtin_amdgcn_s_barrier();

    int buf = 0;
    for (int s = 0; s < NT; ++s) {
        const uint8_t* L = lds + buf * 32768;

        intx8 af[4], bf[2];
        #pragma unroll
        for (int mi = 0; mi < 4; ++mi) {
            intx4 lo = *(const intx4*)(L + aoff[mi]);
            intx4 hi = *(const intx4*)(L + (aoff[mi] ^ 16));
            af[mi] = __builtin_shufflevector(lo, hi, 0, 1, 2, 3, 4, 5, 6, 7);
        }
        #pragma unroll
        for (int ni = 0; ni < 2; ++ni) {
            intx4 lo = *(const intx4*)(L + boff[ni]);
            intx4 hi = *(const intx4*)(L + (boff[ni] ^ 16));
            bf[ni] = __builtin_shufflevector(lo, hi, 0, 1, 2, 3, 4, 5, 6, 7);
        }

        int buf2 = (buf >= 1) ? buf - 1 : 2;   // (buf+2)%3
        if (s + 2 < NT) {
            STAGE(buf2 * 32768, 0, 0, s + 2); STAGE(buf2 * 32768, 0, 1, s + 2);
            STAGE(buf2 * 32768, 1, 0, s + 2); STAGE(buf2 * 32768, 1, 1, s + 2);
        }

        __builtin_amdgcn_s_barrier();
        asm volatile("s_waitcnt lgkmcnt(0)" ::: "memory");
        __builtin_amdgcn_sched_barrier(0);
        __builtin_amdgcn_s_setprio(1);
        #pragma unroll
        for (int mi = 0; mi < 4; ++mi) {
            #pragma unroll
            for (int ni = 0; ni < 2; ++ni) {
                acc[mi][ni] = __builtin_amdgcn_mfma_scale_f32_32x32x64_f8f6f4(
                    af[mi], bf[ni], acc[mi][ni], 0, 0,
                    0, 0x7f7f7f7f, 0, 0x7f7f7f7f);   // E8M0 127 = x1.0 (exact)
            }
        }
        __builtin_amdgcn_s_setprio(0);

        if (s < NT - 2)       asm volatile("s_waitcnt vmcnt(4)" ::: "memory");  // tile s+1 landed
        else if (s == NT - 2) asm volatile("s_waitcnt vmcnt(0)" ::: "memory");  // last tile landed
        __builtin_amdgcn_s_barrier();
        buf = (buf == 2) ? 0 : buf + 1;
    }
#undef STAGE

    float ax = fmaxf(__uint_as_float(amax[0]), EPSF);
    float aw = fmaxf(__uint_as_float(amax[1]), EPSF);
    float dsc = (ax / FP8_MAX) * (aw / FP8_MAX);  // 1/(sx*sw)

    // C/D 32x32 layout: col = lane&31, row = (reg&3) + 8*(reg>>2) + 4*(lane>>5)
    #pragma unroll
    for (int ni = 0; ni < 2; ++ni) {
        int col = tn * BN + wn * 64 + ni * 32 + rl;
        float bv = bias[(long)b * NDIM + col];
        #pragma unroll
        for (int mi = 0; mi < 4; ++mi) {
            int rbase = tm * BM + wm * 128 + mi * 32 + kh * 4;
            #pragma unroll
            for (int r = 0; r < 16; ++r) {
                int grow = rbase + (r & 3) + 8 * (r >> 2);
                out[((long)b * MDIM + grow) * NDIM + col] = acc[mi][ni][r] * dsc + bv;
            }
        }
    }
}

extern "C" void kernel_launch(void* const* d_in, const int* in_sizes, int n_in,
                              void* d_out, int out_size, void* d_ws, size_t ws_size,
                              hipStream_t stream) {
    const float* x = (const float*)d_in[0];
    const float* w = (const float*)d_in[1];
    const float* bias = (const float*)d_in[2];
    float* out = (float*)d_out;

    unsigned int* amax = (unsigned int*)d_ws;
    uint8_t* qx = (uint8_t*)d_ws + QX_OFF;
    uint8_t* qwT = (uint8_t*)d_ws + QW_OFF;
    (void)in_sizes; (void)n_in; (void)out_size; (void)ws_size;

    // zero the amax accumulators (ws is poisoned 0xAA before every launch)
    hipMemsetAsync(d_ws, 0, 8, stream);

    amax_kernel<<<dim3(AMAX_BLOCKS, 2), 256, 0, stream>>>((const float4*)x, (const float4*)w, amax);
    quant_x_kernel<<<QX_BLOCKS, 256, 0, stream>>>((const float4*)x, (uint32_t*)qx, amax);
    quant_w_kernel<<<dim3(NDIM / 64, KDIM / 64, BATCH), 256, 0, stream>>>(w, qwT, amax);
    gemm_kernel<<<dim3(NDIM / BN, MDIM / BM, BATCH), 512, 0, stream>>>(qx, qwT, bias, out, amax);
}